// Round 6
// baseline (171.662 us; speedup 1.0000x reference)
//
#include <hip/hip_runtime.h>

// ---------------------------------------------------------------------------
// SlidingWindowSelfAttention  (B=2, L=2048, D=1024, H=16, hd=64, WINDOW=256)
// R10: (1) opj = R8's gemm_opj reinstated (R9's revert was based on a
//      confounded read: R8's QKV codegen shift (+5.6) masked opj's ~-4).
//      (2) attn: double-buffered K/V LDS, ONE barrier/tile (was 2), global
//      loads issued one tile early into regs (T14) -> HBM latency hidden.
//      (3) QKV frozen at R9 (LDS-read-rate bound: 176 ds_read_b128/CU/tile
//      ~2112 cyc > 1546 cyc MFMA -- barrier micro-scheduling can't help).
// ---------------------------------------------------------------------------

#define SEQ_L 2048
#define WIN   256

typedef __bf16 bf16x8 __attribute__((ext_vector_type(8)));
typedef float  f32x4  __attribute__((ext_vector_type(4)));

template<int X> struct ic { static constexpr int v = X; };

__device__ __forceinline__ unsigned short f32_to_bf16(float f) {
  unsigned int u = __float_as_uint(f);
  u += 0x7FFFu + ((u >> 16) & 1u);      // round-to-nearest-even
  return (unsigned short)(u >> 16);
}

// async global->LDS, 16 B/lane; lds base must be wave-uniform (m104/m108)
__device__ __forceinline__ void async16(const unsigned short* g, unsigned short* l) {
  __builtin_amdgcn_global_load_lds(
      (const __attribute__((address_space(1))) unsigned int*)g,
      (__attribute__((address_space(3))) unsigned int*)l, 16, 0, 0);
}

// ---- fused fp32 -> bf16 cast for x, w1, w2 ----
__global__ void cast_all(const float* __restrict__ x,  unsigned short* __restrict__ xo,
                         const float* __restrict__ w1, unsigned short* __restrict__ w1o,
                         const float* __restrict__ w2, unsigned short* __restrict__ w2o) {
  int i = blockIdx.x * 256 + threadIdx.x;          // 2,097,152 float4 groups
  const float* in; unsigned short* out; int k;
  if (i < 1048576)       { in = x;  out = xo;  k = i; }
  else if (i < 1835008)  { in = w1; out = w1o; k = i - 1048576; }
  else                   { in = w2; out = w2o; k = i - 1835008; }
  float4 v = ((const float4*)in)[k];
  ushort4 o;
  o.x = f32_to_bf16(v.x); o.y = f32_to_bf16(v.y);
  o.z = f32_to_bf16(v.z); o.w = f32_to_bf16(v.w);
  ((ushort4*)out)[k] = o;
}

// ---------------------------------------------------------------------------
// QKV GEMM: C[4096,3072] = A[4096,1024] @ Bt[3072,1024]^T + bias, bf16 out.
// 256x192 tile, BK=64, 512 thr = 8 waves (2M x 4N). R9 schedule, frozen.
// ---------------------------------------------------------------------------
__global__ __launch_bounds__(512, 2) void gemm_qkv(
    const unsigned short* __restrict__ A,
    const unsigned short* __restrict__ Bt,
    const float* __restrict__ bias,
    unsigned short* __restrict__ C, int M, int N, int K)
{
  __shared__ unsigned short As[2][256 * 64];
  __shared__ unsigned short Bs[2][192 * 64];

  const int tid  = threadIdx.x;
  const int lane = tid & 63;
  const int w    = tid >> 6;          // 0..7
  const int wr   = w >> 2;            // 0..1  M-half
  const int wc   = w & 3;             // 0..3  N-quarter (48 cols each)
  const int quad = lane >> 4;
  const int l16  = lane & 15;
  const int lrow = (lane >> 3) & 7;   // staging row-within-8
  const int scol = (lane & 7) ^ lrow; // swizzled source chunk (st-swizzle)

  const long m0 = (long)blockIdx.y * 256;
  const long n0 = (long)blockIdx.x * 192;

  f32x4 acc[8][3];
#pragma unroll
  for (int i = 0; i < 8; ++i)
#pragma unroll
    for (int j = 0; j < 3; ++j)
#pragma unroll
      for (int r = 0; r < 4; ++r) acc[i][j][r] = 0.0f;

  auto stA = [&](int buf, int c, int kc) {
    async16(A + (m0 + c * 64 + w * 8 + lrow) * (long)K + kc + scol * 8,
            &As[buf][(c * 64 + w * 8) * 64]);
  };
  auto stB = [&](int buf, int c, int kc) {
    async16(Bt + (n0 + c * 64 + w * 8 + lrow) * (long)K + kc + scol * 8,
            &Bs[buf][(c * 64 + w * 8) * 64]);
  };
  auto hA0 = [&](int buf, int kc) { stA(buf, 0, kc); stA(buf, 2, kc); };
  auto hA1 = [&](int buf, int kc) { stA(buf, 1, kc); stA(buf, 3, kc); };
  auto hB  = [&](int buf, int kc) { stB(buf, 0, kc); stB(buf, 1, kc); stB(buf, 2, kc); };

  auto rdA = [&](bf16x8 (&af)[4], int buf, int QM, int kh) {
#pragma unroll
    for (int mi = 0; mi < 4; ++mi) {
      int rr = wr * 128 + QM * 64 + mi * 16 + l16;
      af[mi] = *(const bf16x8*)&As[buf][rr * 64 + (((kh * 4 + quad) ^ (rr & 7)) << 3)];
    }
  };
  auto rdB = [&](bf16x8 (&bq)[3], int buf, int kh) {
#pragma unroll
    for (int ni = 0; ni < 3; ++ni) {
      int rb = wc * 48 + ni * 16 + l16;
      bq[ni] = *(const bf16x8*)&Bs[buf][rb * 64 + (((kh * 4 + quad) ^ (rb & 7)) << 3)];
    }
  };
  auto cluster = [&](bf16x8 (&af)[4], bf16x8 (&bq)[3], int mb) {
    __builtin_amdgcn_s_setprio(1);
#pragma unroll
    for (int mi = 0; mi < 4; ++mi)
#pragma unroll
      for (int ni = 0; ni < 3; ++ni)
        acc[mb + mi][ni] = __builtin_amdgcn_mfma_f32_16x16x32_bf16(
            bq[ni], af[mi], acc[mb + mi][ni], 0, 0, 0);
    __builtin_amdgcn_s_setprio(0);
  };
  auto lgkm = [](auto n) {   // staged DS wait; DS completes in issue order
    constexpr int V = decltype(n)::v;
    if constexpr (V == 8)      asm volatile("s_waitcnt lgkmcnt(8)" ::: "memory");
    else if constexpr (V == 4) asm volatile("s_waitcnt lgkmcnt(4)" ::: "memory");
    else                       asm volatile("s_waitcnt lgkmcnt(0)" ::: "memory");
    __builtin_amdgcn_sched_barrier(0);   // rule 18: pin MFMA after the wait
  };
  auto vmw = [](auto n) {
    constexpr int V = decltype(n)::v;
    if constexpr (V == 7)      asm volatile("s_waitcnt vmcnt(7)" ::: "memory");
    else if constexpr (V == 2) asm volatile("s_waitcnt vmcnt(2)" ::: "memory");
    else if constexpr (V == 0) asm volatile("s_waitcnt vmcnt(0)" ::: "memory");
  };

  // ---- prologue: [A0(0) B(0)] [A1(0)] [A0(1) B(1)] = 12 loads ----
  hA0(0, 0); hB(0, 0); hA1(0, 0); hA0(1, 64); hB(1, 64);
  asm volatile("s_waitcnt vmcnt(7)" ::: "memory");   // A0(0),B(0) landed
  __builtin_amdgcn_s_barrier();

  auto tile = [&](int T, auto s1, auto s4, auto vS, auto vE) {
    const int buf = T & 1;
    bf16x8 af00[4], af10[4], af01[4], af11[4], bq0[3], bq1[3];
    rdA(af00, buf, 0, 0);
    rdB(bq0,  buf, 0);
    rdA(af01, buf, 0, 1);
    rdB(bq1,  buf, 1);
    if constexpr (decltype(s1)::v) hA1(buf ^ 1, (T + 1) * 64);
    vmw(vS);                              // retire A1(T)
    __builtin_amdgcn_s_barrier();         // BAR1: publish A1(T)
    rdA(af10, buf, 1, 0);
    rdA(af11, buf, 1, 1);
    lgkm(ic<8>{});                        // front 14 done
    cluster(af00, bq0, 0);                // p1
    lgkm(ic<4>{});                        // af10 done
    cluster(af10, bq0, 4);                // p2
    cluster(af01, bq1, 0);                // p3
    lgkm(ic<0>{});                        // all buf(T) reads drained
    __builtin_amdgcn_s_barrier();         // BAR2: safe to overwrite A0/B(T)
    if constexpr (decltype(s4)::v) { hA0(buf, (T + 2) * 64); hB(buf, (T + 2) * 64); }
    cluster(af11, bq1, 4);                // p4
    if constexpr (decltype(vE)::v >= 0) vmw(vE);   // retire A0/B(T+1)
    __builtin_amdgcn_s_barrier();         // BAR3: publish A0/B(T+1)
  };

  const int NT = K >> 6;               // 16; requires NT >= 3
#pragma unroll 1
  for (int T = 0; T < NT - 2; ++T) tile(T, ic<1>{}, ic<1>{}, ic<7>{}, ic<7>{});
  tile(NT - 2, ic<1>{}, ic<0>{}, ic<7>{}, ic<2>{});
  tile(NT - 1, ic<0>{}, ic<0>{}, ic<0>{}, ic<-1>{});

  // ---- epilogue: thread (quad,l16) holds C[m][nb..nb+3] -> ushort4 store ---
#pragma unroll
  for (int ni = 0; ni < 3; ++ni) {
    const int nb = wc * 48 + ni * 16 + quad * 4;
    const float4 bv = *(const float4*)&bias[n0 + nb];
#pragma unroll
    for (int qm = 0; qm < 2; ++qm)
#pragma unroll
      for (int mi = 0; mi < 4; ++mi) {
        long m = m0 + wr * 128 + qm * 64 + mi * 16 + l16;
        f32x4 a = acc[qm * 4 + mi][ni];
        ushort4 o;
        o.x = f32_to_bf16(a[0] + bv.x);
        o.y = f32_to_bf16(a[1] + bv.y);
        o.z = f32_to_bf16(a[2] + bv.z);
        o.w = f32_to_bf16(a[3] + bv.w);
        *(ushort4*)&C[m * (long)N + n0 + nb] = o;
      }
  }
}

// ---------------------------------------------------------------------------
// Out-projection GEMM: C[4096,1024] fp32 = A[4096,1024] @ Bt[1024,1024]^T + b.
// 128x128 tile, BK=64, 512 thr = 8 waves (2M x 4N), per-wave 64x32.
// LDS 64 KiB -> 2 blocks/CU (4 waves/SIMD). R8-verified (passed, absmax ok).
// ---------------------------------------------------------------------------
__global__ __launch_bounds__(512, 4) void gemm_opj(
    const unsigned short* __restrict__ A,
    const unsigned short* __restrict__ Bt,
    const float* __restrict__ bias,
    float* __restrict__ C, int M, int N, int K)
{
  __shared__ unsigned short As[2][128 * 64];
  __shared__ unsigned short Bs[2][128 * 64];

  const int tid  = threadIdx.x;
  const int lane = tid & 63;
  const int w    = tid >> 6;          // 0..7
  const int wr   = w >> 2;            // 0..1  M-half (64 rows)
  const int wc   = w & 3;             // 0..3  N-quarter (32 cols)
  const int quad = lane >> 4;
  const int l16  = lane & 15;
  const int lrow = (lane >> 3) & 7;
  const int scol = (lane & 7) ^ lrow;

  const long m0 = (long)blockIdx.y * 128;
  const long n0 = (long)blockIdx.x * 128;

  f32x4 acc[4][2];
#pragma unroll
  for (int i = 0; i < 4; ++i)
#pragma unroll
    for (int j = 0; j < 2; ++j)
#pragma unroll
      for (int r = 0; r < 4; ++r) acc[i][j][r] = 0.0f;

  auto stage = [&](int buf, int kc) {
#pragma unroll
    for (int c = 0; c < 2; ++c)
      async16(A + (m0 + c * 64 + w * 8 + lrow) * (long)K + kc + scol * 8,
              &As[buf][(c * 64 + w * 8) * 64]);
#pragma unroll
    for (int c = 0; c < 2; ++c)
      async16(Bt + (n0 + c * 64 + w * 8 + lrow) * (long)K + kc + scol * 8,
              &Bs[buf][(c * 64 + w * 8) * 64]);
  };

  auto rdA = [&](bf16x8 (&af)[4], int buf, int kh) {
#pragma unroll
    for (int mi = 0; mi < 4; ++mi) {
      int rr = wr * 64 + mi * 16 + l16;
      af[mi] = *(const bf16x8*)&As[buf][rr * 64 + (((kh * 4 + quad) ^ (rr & 7)) << 3)];
    }
  };
  auto rdB = [&](bf16x8 (&bq)[2], int buf, int kh) {
#pragma unroll
    for (int ni = 0; ni < 2; ++ni) {
      int rb = wc * 32 + ni * 16 + l16;
      bq[ni] = *(const bf16x8*)&Bs[buf][rb * 64 + (((kh * 4 + quad) ^ (rb & 7)) << 3)];
    }
  };
  auto cluster = [&](bf16x8 (&af)[4], bf16x8 (&bq)[2]) {
    __builtin_amdgcn_s_setprio(1);
#pragma unroll
    for (int mi = 0; mi < 4; ++mi)
#pragma unroll
      for (int ni = 0; ni < 2; ++ni)
        acc[mi][ni] = __builtin_amdgcn_mfma_f32_16x16x32_bf16(
            bq[ni], af[mi], acc[mi][ni], 0, 0, 0);
    __builtin_amdgcn_s_setprio(0);
  };
  auto lgkm0 = [] {
    asm volatile("s_waitcnt lgkmcnt(0)" ::: "memory");
    __builtin_amdgcn_sched_barrier(0);
  };

  // prologue: T0 -> buf0, T1 -> buf1; publish T0
  stage(0, 0); stage(1, 64);
  asm volatile("s_waitcnt vmcnt(4)" ::: "memory");
  __builtin_amdgcn_s_barrier();

  auto tile = [&](int T, auto s, auto v) {
    const int buf = T & 1;
    bf16x8 af[4], bq[2];
    rdA(af, buf, 0);
    rdB(bq, buf, 0);
    lgkm0();
    cluster(af, bq);
    rdA(af, buf, 1);
    rdB(bq, buf, 1);
    lgkm0();
    __builtin_amdgcn_s_barrier();      // all buf(T) reads complete
    if constexpr (decltype(s)::v) stage(buf, (T + 2) * 64);
    cluster(af, bq);
    if constexpr (decltype(v)::v == 4)
      asm volatile("s_waitcnt vmcnt(4)" ::: "memory");
    else if constexpr (decltype(v)::v == 0)
      asm volatile("s_waitcnt vmcnt(0)" ::: "memory");
    __builtin_amdgcn_s_barrier();      // publish T+1 to all waves
  };

  const int NT = K >> 6;               // 16; requires NT >= 3
#pragma unroll 1
  for (int T = 0; T < NT - 2; ++T) tile(T, ic<1>{}, ic<4>{});
  tile(NT - 2, ic<0>{}, ic<0>{});
  tile(NT - 1, ic<0>{}, ic<-1>{});

  // epilogue: thread (quad,l16) holds C[m][nb..nb+3] -> float4 store
#pragma unroll
  for (int ni = 0; ni < 2; ++ni) {
    const int nb = wc * 32 + ni * 16 + quad * 4;
    const float4 bv = *(const float4*)&bias[n0 + nb];
#pragma unroll
    for (int mi = 0; mi < 4; ++mi) {
      long m = m0 + wr * 64 + mi * 16 + l16;
      f32x4 a = acc[mi][ni];
      float4 o;
      o.x = a[0] + bv.x;
      o.y = a[1] + bv.y;
      o.z = a[2] + bv.z;
      o.w = a[3] + bv.w;
      *(float4*)&C[m * (long)N + n0 + nb] = o;
    }
  }
}

// ---------------------------------------------------------------------------
// Windowed flash attention, no-max softmax, 128 queries/block.
// R10: double-buffered K/V LDS (ping-pong), ONE __syncthreads per tile,
// global loads for tile t+2 issued during tile t (regs held one full tile ->
// HBM latency hidden). Write-after-read safety: writes to buf X during tile t
// occur after the end-of-(t-1) barrier, which drained all tile-(t-1) reads
// of X (syncthreads emits full vm/lgkm drain). LDS 46 KB -> 3 blocks/CU.
// ---------------------------------------------------------------------------
__global__ __launch_bounds__(256) void attn_kernel(
    const unsigned short* __restrict__ qkv,
    unsigned short* __restrict__ aout)
{
  __shared__ unsigned short Ks[2][64 * 72];    // [buf][key][d]
  __shared__ unsigned short Vt[2][64 * 72];    // [buf][d][key^swz]
  __shared__ unsigned short Ps[4 * 16 * 72];   // per-wave [q][key]

  const int tid  = threadIdx.x;
  const int w    = tid >> 6;
  const int lane = tid & 63;
  const int quad = lane >> 4;
  const int l16  = lane & 15;

  const int blk = blockIdx.x;            // 512 = b(2) * h(16) * 16 q-blocks
  const int qb  = blk & 15;
  const int h   = (blk >> 4) & 15;
  const int b   = blk >> 8;

  const int  i0 = qb * 128;
  const long rowbase = (long)b * SEQ_L;

  // Q fragments for both subtiles: A[m=l16][k=quad*8+j] (+32)
  bf16x8 aq[2][2];
#pragma unroll
  for (int sub = 0; sub < 2; ++sub) {
    const unsigned short* qp =
        qkv + (rowbase + i0 + sub * 64 + w * 16 + l16) * 3072 + h * 64 + quad * 8;
    aq[sub][0] = *(const bf16x8*)(qp);
    aq[sub][1] = *(const bf16x8*)(qp + 32);
  }

  f32x4 o[2][4];
  float l_i[2][4];
#pragma unroll
  for (int sub = 0; sub < 2; ++sub)
#pragma unroll
    for (int ni = 0; ni < 4; ++ni)
#pragma unroll
      for (int r = 0; r < 4; ++r) { o[sub][ni][r] = 0.0f; l_i[sub][r] = 0.0f; }

  unsigned short* psw = &Ps[w * 16 * 72];

  const int j_begin = (i0 >= WIN) ? i0 - WIN : 0;
  const int j_end   = i0 + 128;

  // ---- staged K/V: regs hold the NEXT tile; written to LDS one tile later
  uint4 nk[2], nv[2];
  auto load_tile = [&](int j0) {
#pragma unroll
    for (int p = 0; p < 2; ++p) {
      int c = p * 256 + tid, row = c >> 3, col8 = c & 7;
      const unsigned short* base = qkv + (rowbase + j0 + row) * 3072 + h * 64 + col8 * 8;
      nk[p] = *(const uint4*)(base + 1024);
      nv[p] = *(const uint4*)(base + 2048);
    }
  };
  auto write_tile = [&](int bi) {
#pragma unroll
    for (int p = 0; p < 2; ++p) {
      int c = p * 256 + tid, row = c >> 3, col8 = c & 7;
      *(uint4*)(&Ks[bi][row * 72 + col8 * 8]) = nk[p];
      unsigned short tmp[8];
      *(uint4*)tmp = nv[p];
      int rsw = row ^ (col8 << 3);
#pragma unroll
      for (int e = 0; e < 8; ++e)
        Vt[bi][(col8 * 8 + e) * 72 + rsw] = tmp[e];
    }
  };

  // prologue: tile0 -> buf0 (latency exposed once), issue tile1 loads
  load_tile(j_begin);
  write_tile(0);
  if (j_begin + 64 < j_end) load_tile(j_begin + 64);
  __syncthreads();

  int cur = 0;
  for (int j0 = j_begin; j0 < j_end; j0 += 64) {
    // ---- hoist K and V fragments from buf[cur] ----
    bf16x8 kf[4][2];
#pragma unroll
    for (int g = 0; g < 4; ++g) {
      kf[g][0] = *(const bf16x8*)(&Ks[cur][(g * 16 + l16) * 72 + quad * 8]);
      kf[g][1] = *(const bf16x8*)(&Ks[cur][(g * 16 + l16) * 72 + 32 + quad * 8]);
    }
    bf16x8 vf[2][4];
#pragma unroll
    for (int kk = 0; kk < 2; ++kk)
#pragma unroll
      for (int ni = 0; ni < 4; ++ni) {
        int d  = ni * 16 + l16;
        int rb = (kk * 32 + quad * 8) ^ (((d >> 3) & 7) << 3);
        vf[kk][ni] = *(const bf16x8*)(&Vt[cur][d * 72 + rb]);
      }

#pragma unroll
    for (int sub = 0; sub < 2; ++sub) {
      const int i0s = i0 + sub * 64 + w * 16;
      if (j0 > i0s + 15) continue;              // entirely in the future
      if (j0 + 63 + WIN <= i0s) continue;       // entirely before the window

      // ---- S = Q.K^T ----
      f32x4 s[4];
#pragma unroll
      for (int g = 0; g < 4; ++g) {
        f32x4 z;
#pragma unroll
        for (int r = 0; r < 4; ++r) z[r] = 0.0f;
        z = __builtin_amdgcn_mfma_f32_16x16x32_bf16(aq[sub][0], kf[g][0], z, 0, 0, 0);
        z = __builtin_amdgcn_mfma_f32_16x16x32_bf16(aq[sub][1], kf[g][1], z, 0, 0, 0);
        s[g] = z;
      }
      // ---- mask + exp (no max subtraction) + P write + local l ----
#pragma unroll
      for (int g = 0; g < 4; ++g) {
        int j = j0 + g * 16 + l16;
#pragma unroll
        for (int r = 0; r < 4; ++r) {
          int i = i0s + quad * 4 + r;
          bool ok = (j <= i) && (j > i - WIN);
          float e = ok ? __expf(s[g][r] * 0.125f) : 0.0f;
          psw[(quad * 4 + r) * 72 + g * 16 + l16] = f32_to_bf16(e);
          l_i[sub][r] += e;
        }
      }
      asm volatile("s_waitcnt lgkmcnt(0)" ::: "memory");  // P visible to own wave
      // ---- O += P.V ----
#pragma unroll
      for (int kk = 0; kk < 2; ++kk) {
        bf16x8 ap = *(const bf16x8*)(&psw[l16 * 72 + kk * 32 + quad * 8]);
#pragma unroll
        for (int ni = 0; ni < 4; ++ni)
          o[sub][ni] = __builtin_amdgcn_mfma_f32_16x16x32_bf16(ap, vf[kk][ni], o[sub][ni], 0, 0, 0);
      }
    }

    // ---- staged write of tile t+1 into buf^1; issue loads for tile t+2 ----
    if (j0 + 64 < j_end) {
      write_tile(cur ^ 1);
      if (j0 + 128 < j_end) load_tile(j0 + 128);
    }
    __syncthreads();     // publish buf^1 writes; drain this tile's buf reads
    cur ^= 1;
  }

  // ---- epilogue: one l-reduction, normalize, store bf16 [token][h*64+d] ----
#pragma unroll
  for (int sub = 0; sub < 2; ++sub)
#pragma unroll
    for (int r = 0; r < 4; ++r) {
      float rs = l_i[sub][r];
      rs += __shfl_xor(rs, 1);
      rs += __shfl_xor(rs, 2);
      rs += __shfl_xor(rs, 4);
      rs += __shfl_xor(rs, 8);
      float inv_l = 1.0f / rs;
      long row = rowbase + i0 + sub * 64 + w * 16 + quad * 4 + r;
#pragma unroll
      for (int ni = 0; ni < 4; ++ni)
        aout[row * 1024 + h * 64 + ni * 16 + l16] = f32_to_bf16(o[sub][ni][r] * inv_l);
    }
}

// ---------------------------------------------------------------------------
extern "C" void kernel_launch(void* const* d_in, const int* in_sizes, int n_in,
                              void* d_out, int out_size, void* d_ws, size_t ws_size,
                              hipStream_t stream)
{
  const float* x  = (const float*)d_in[0];   // [2,2048,1024]
  const float* w1 = (const float*)d_in[1];   // [3072,1024]
  const float* b1 = (const float*)d_in[2];   // [3072]
  const float* w2 = (const float*)d_in[3];   // [1024,1024]
  const float* b2 = (const float*)d_in[4];   // [1024]
  float* out = (float*)d_out;                // [2,2048,1024] fp32

  char* ws = (char*)d_ws;
  unsigned short* x_bf   = (unsigned short*)(ws);              //  8.39 MB
  unsigned short* w1_bf  = (unsigned short*)(ws + 8388608);    //  6.29 MB
  unsigned short* w2_bf  = (unsigned short*)(ws + 14680064);   //  2.10 MB
  unsigned short* qkv_bf = (unsigned short*)(ws + 16777216);   // 25.17 MB
  unsigned short* at_bf  = (unsigned short*)(ws + 41943040);   //  8.39 MB

  cast_all<<<8192, 256, 0, stream>>>(x, x_bf, w1, w1_bf, w2, w2_bf);

  dim3 g1(3072 / 192, 4096 / 256);   // (16, 16) = 256 blocks, 512 thr
  gemm_qkv<<<g1, 512, 0, stream>>>(x_bf, w1_bf, b1, qkv_bf, 4096, 3072, 1024);

  attn_kernel<<<512, 256, 0, stream>>>(qkv_bf, at_bf);

  dim3 g2(1024 / 128, 4096 / 128);   // (8, 32) = 256 blocks, 512 thr
  gemm_opj<<<g2, 512, 0, stream>>>(at_bf, w2_bf, b2, out, 4096, 1024, 1024);
}

// Round 7
// 153.760 us; speedup vs baseline: 1.1164x; 1.1164x over previous
//
#include <hip/hip_runtime.h>

// ---------------------------------------------------------------------------
// SlidingWindowSelfAttention  (B=2, L=2048, D=1024, H=16, hd=64, WINDOW=256)
// R11 = exact R7 restoration (measured best: 154.9 us).
//   Factor matrix over R7-R10: R7 argmax; gemm_opj's isolated -3.8 is
//   outweighed by co-compilation perturbation (+5.6 on QKV, rule #19);
//   R9 QKV resched +2.6; R10 dbuf-attn ~+12 (mechanism unidentified).
//   QKV: 256x192 tile, 4-phase, 3 barriers/tile, counted vmcnt(7),
//   swapped-operand MFMA -> ushort4 stores. opj: m97-style 64^2 gemm_nt.
//   attn: single-buffer windowed flash, no-max softmax.
// ---------------------------------------------------------------------------

#define SEQ_L 2048
#define WIN   256

typedef __bf16 bf16x8 __attribute__((ext_vector_type(8)));
typedef float  f32x4  __attribute__((ext_vector_type(4)));

template<int X> struct ic { static constexpr int v = X; };

__device__ __forceinline__ unsigned short f32_to_bf16(float f) {
  unsigned int u = __float_as_uint(f);
  u += 0x7FFFu + ((u >> 16) & 1u);      // round-to-nearest-even
  return (unsigned short)(u >> 16);
}

// async global->LDS, 16 B/lane; lds base must be wave-uniform (m104/m108)
__device__ __forceinline__ void async16(const unsigned short* g, unsigned short* l) {
  __builtin_amdgcn_global_load_lds(
      (const __attribute__((address_space(1))) unsigned int*)g,
      (__attribute__((address_space(3))) unsigned int*)l, 16, 0, 0);
}

// ---- fused fp32 -> bf16 cast for x, w1, w2 ----
__global__ void cast_all(const float* __restrict__ x,  unsigned short* __restrict__ xo,
                         const float* __restrict__ w1, unsigned short* __restrict__ w1o,
                         const float* __restrict__ w2, unsigned short* __restrict__ w2o) {
  int i = blockIdx.x * 256 + threadIdx.x;          // 2,097,152 float4 groups
  const float* in; unsigned short* out; int k;
  if (i < 1048576)       { in = x;  out = xo;  k = i; }
  else if (i < 1835008)  { in = w1; out = w1o; k = i - 1048576; }
  else                   { in = w2; out = w2o; k = i - 1835008; }
  float4 v = ((const float4*)in)[k];
  ushort4 o;
  o.x = f32_to_bf16(v.x); o.y = f32_to_bf16(v.y);
  o.z = f32_to_bf16(v.z); o.w = f32_to_bf16(v.w);
  ((ushort4*)out)[k] = o;
}

// ---------------------------------------------------------------------------
// QKV GEMM: C[4096,3072] = A[4096,1024] @ Bt[3072,1024]^T + bias, bf16 out.
// 256x192 tile, BK=64, 512 thr = 8 waves (2M x 4N), per-wave 128x48.
// Phases per K-tile (QM, kh): p1=(0,kh0) p2=(1,kh0) p3=(0,kh1) p4=(1,kh1).
// Reads: af (4/phase, fresh), bq (3, read at p1/p3, HELD across the QM pair)
// => 22 ds_read_b128 / wave / tile (minimal).  MFMA: 12/phase (operands
// SWAPPED: mfma(bq, af, acc) so each thread's f32x4 = 4 consecutive C-cols
// of one row -> ushort4 epilogue stores).
// Staging per tile: p1 issues A1(T+1)->buf^1 (legal: last read of A1(T-1) is
// p4(T-1), lgkmcnt(0)'d + barrier'd); p4 issues A0(T+2)+B(T+2)->buf (legal:
// last reads of A0(T)/B(T) are p3(T), barrier'd at end-p3).
// Per-wave vmcnt ledger (each wave stages its own 8-row slices; pre-barrier
// vmcnt publishes its slice, barrier publishes all): steady outstanding after
// end-p4 = A1(T+1)[2]+A0(T+2)[2]+B(T+2)[3] = 7.  end-p1: issue 2 -> vmcnt(7)
// retires exactly A1(T) (read at p2).  end-p4: issue 5 -> vmcnt(7) retires
// exactly A0B(T+1) (read at p1(T+1)).  Tail peels 7 -> 2 -> 0.
// Barriers: end-p1, end-p3, end-p4 only (p2->p3 has no cross-wave hazard).
// LDS: (256+192)*64*2B*2buf = 112 KiB -> 1 block/CU. Requires NT >= 3.
// ---------------------------------------------------------------------------
__global__ __launch_bounds__(512, 2) void gemm_qkv(
    const unsigned short* __restrict__ A,
    const unsigned short* __restrict__ Bt,
    const float* __restrict__ bias,
    unsigned short* __restrict__ C, int M, int N, int K)
{
  __shared__ unsigned short As[2][256 * 64];
  __shared__ unsigned short Bs[2][192 * 64];

  const int tid  = threadIdx.x;
  const int lane = tid & 63;
  const int w    = tid >> 6;          // 0..7
  const int wr   = w >> 2;            // 0..1  M-half
  const int wc   = w & 3;             // 0..3  N-quarter (48 cols each)
  const int quad = lane >> 4;
  const int l16  = lane & 15;
  const int lrow = (lane >> 3) & 7;   // staging row-within-8
  const int scol = (lane & 7) ^ lrow; // swizzled source chunk (st-swizzle)

  const long m0 = (long)blockIdx.y * 256;
  const long n0 = (long)blockIdx.x * 192;

  f32x4 acc[8][3];
#pragma unroll
  for (int i = 0; i < 8; ++i)
#pragma unroll
    for (int j = 0; j < 3; ++j)
#pragma unroll
      for (int r = 0; r < 4; ++r) acc[i][j][r] = 0.0f;

  auto stA = [&](int buf, int c, int kc) {
    async16(A + (m0 + c * 64 + w * 8 + lrow) * (long)K + kc + scol * 8,
            &As[buf][(c * 64 + w * 8) * 64]);
  };
  auto stB = [&](int buf, int c, int kc) {
    async16(Bt + (n0 + c * 64 + w * 8 + lrow) * (long)K + kc + scol * 8,
            &Bs[buf][(c * 64 + w * 8) * 64]);
  };
  auto hA0 = [&](int buf, int kc) { stA(buf, 0, kc); stA(buf, 2, kc); }; // rows 0-63,128-191
  auto hA1 = [&](int buf, int kc) { stA(buf, 1, kc); stA(buf, 3, kc); }; // rows 64-127,192-255
  auto hB  = [&](int buf, int kc) { stB(buf, 0, kc); stB(buf, 1, kc); stB(buf, 2, kc); };

  auto rdA = [&](bf16x8 (&af)[4], int buf, int QM, int kh) {
#pragma unroll
    for (int mi = 0; mi < 4; ++mi) {
      int rr = wr * 128 + QM * 64 + mi * 16 + l16;
      af[mi] = *(const bf16x8*)&As[buf][rr * 64 + (((kh * 4 + quad) ^ (rr & 7)) << 3)];
    }
  };
  auto rdB = [&](bf16x8 (&bq)[3], int buf, int kh) {
#pragma unroll
    for (int ni = 0; ni < 3; ++ni) {
      int rb = wc * 48 + ni * 16 + l16;
      bq[ni] = *(const bf16x8*)&Bs[buf][rb * 64 + (((kh * 4 + quad) ^ (rb & 7)) << 3)];
    }
  };
  // operand-swapped: D "row"(quad,reg) axis = bq's index (C-col),
  // D "col"(l16) axis = af's index (C-row) -> thread holds 4 consecutive cols.
  auto cluster = [&](bf16x8 (&af)[4], bf16x8 (&bq)[3], int mb) {
    __builtin_amdgcn_s_setprio(1);
#pragma unroll
    for (int mi = 0; mi < 4; ++mi)
#pragma unroll
      for (int ni = 0; ni < 3; ++ni)
        acc[mb + mi][ni] = __builtin_amdgcn_mfma_f32_16x16x32_bf16(
            bq[ni], af[mi], acc[mb + mi][ni], 0, 0, 0);
    __builtin_amdgcn_s_setprio(0);
  };
  auto lgkm0 = [] {
    asm volatile("s_waitcnt lgkmcnt(0)" ::: "memory");
    __builtin_amdgcn_sched_barrier(0);   // rule 18: pin MFMA after the wait
  };
  auto vmw = [](auto n) {
    constexpr int V = decltype(n)::v;
    if constexpr (V == 7)      asm volatile("s_waitcnt vmcnt(7)" ::: "memory");
    else if constexpr (V == 2) asm volatile("s_waitcnt vmcnt(2)" ::: "memory");
    else if constexpr (V == 0) asm volatile("s_waitcnt vmcnt(0)" ::: "memory");
  };

  // ---- prologue: [A0(0) B(0)] [A1(0)] [A0(1) B(1)] = 12 loads ----
  hA0(0, 0); hB(0, 0); hA1(0, 0); hA0(1, 64); hB(1, 64);
  asm volatile("s_waitcnt vmcnt(7)" ::: "memory");   // A0(0),B(0) landed
  __builtin_amdgcn_s_barrier();

  auto tile = [&](int T, auto s1, auto s4, auto v1, auto v4) {
    const int buf = T & 1;
    bf16x8 af[4], bq0[3], bq1[3];
    // ---- p1 (QM0, kh0) + issue A1(T+1) ----
    rdA(af, buf, 0, 0);
    rdB(bq0, buf, 0);
    if constexpr (decltype(s1)::v) hA1(buf ^ 1, (T + 1) * 64);
    lgkm0();
    cluster(af, bq0, 0);
    vmw(v1);
    __builtin_amdgcn_s_barrier();
    // ---- p2 (QM1, kh0): bq0 held ----
    rdA(af, buf, 1, 0);
    lgkm0();
    cluster(af, bq0, 4);
    // ---- p3 (QM0, kh1): no barrier before (no cross-wave hazard) ----
    rdA(af, buf, 0, 1);
    rdB(bq1, buf, 1);
    lgkm0();
    cluster(af, bq1, 0);
    __builtin_amdgcn_s_barrier();      // last consumers of A0(T)/B(T) done
    // ---- p4 (QM1, kh1) + issue A0(T+2), B(T+2) ----
    rdA(af, buf, 1, 1);
    if constexpr (decltype(s4)::v) { hA0(buf, (T + 2) * 64); hB(buf, (T + 2) * 64); }
    lgkm0();
    cluster(af, bq1, 4);
    vmw(v4);
    __builtin_amdgcn_s_barrier();
  };

  const int NT = K >> 6;               // 16; requires NT >= 3
#pragma unroll 1
  for (int T = 0; T < NT - 2; ++T) tile(T, ic<1>{}, ic<1>{}, ic<7>{}, ic<7>{});
  tile(NT - 2, ic<1>{}, ic<0>{}, ic<7>{}, ic<2>{});
  tile(NT - 1, ic<0>{}, ic<0>{}, ic<0>{}, ic<-1>{});

  // ---- epilogue: thread (quad,l16) holds C[m][nb..nb+3] -> ushort4 store ---
#pragma unroll
  for (int ni = 0; ni < 3; ++ni) {
    const int nb = wc * 48 + ni * 16 + quad * 4;
    const float4 bv = *(const float4*)&bias[n0 + nb];
#pragma unroll
    for (int qm = 0; qm < 2; ++qm)
#pragma unroll
      for (int mi = 0; mi < 4; ++mi) {
        long m = m0 + wr * 128 + qm * 64 + mi * 16 + l16;
        f32x4 a = acc[qm * 4 + mi][ni];
        ushort4 o;
        o.x = f32_to_bf16(a[0] + bv.x);
        o.y = f32_to_bf16(a[1] + bv.y);
        o.z = f32_to_bf16(a[2] + bv.z);
        o.w = f32_to_bf16(a[3] + bv.w);
        *(ushort4*)&C[m * (long)N + n0 + nb] = o;
      }
  }
}

// ---------------------------------------------------------------------------
// C[M,N] = A[M,K] @ Bt[N,K]^T + bias   (bf16 in, fp32 accum), m97 structure.
// Kept for the out-projection (64x64 tile, 1024 blocks = 4/CU).
// ---------------------------------------------------------------------------
template<int TBM, int TBN, int MI, int NI, int OUTBF>
__global__ __launch_bounds__(256) void gemm_nt(
    const unsigned short* __restrict__ A,
    const unsigned short* __restrict__ Bt,
    const float* __restrict__ bias,
    void* __restrict__ Cout, int M, int N, int K)
{
  __shared__ unsigned short As[TBM * 64];
  __shared__ unsigned short Bs[TBN * 64];

  const int tid  = threadIdx.x;
  const int lane = tid & 63;
  const int wave = tid >> 6;
  const int wr   = (wave >> 1) * (MI * 16);
  const int wc   = (wave & 1) * (NI * 16);
  const int quad = lane >> 4;
  const int l16  = lane & 15;
  const int lrow = lane >> 3;            // staging row-within-8
  const int scol = (lane & 7) ^ lrow;    // swizzled source chunk

  const long m0 = (long)blockIdx.y * TBM;
  const long n0 = (long)blockIdx.x * TBN;

  f32x4 acc[MI][NI];
#pragma unroll
  for (int i = 0; i < MI; ++i)
#pragma unroll
    for (int j = 0; j < NI; ++j)
#pragma unroll
      for (int r = 0; r < 4; ++r) acc[i][j][r] = 0.0f;

  for (int k0 = 0; k0 < K; k0 += 64) {
#pragma unroll
    for (int p = 0; p < TBM / 32; ++p) {
      int rb = wave * (TBM / 4) + p * 8;
      async16(A + (m0 + rb + lrow) * (long)K + k0 + scol * 8, &As[rb * 64]);
    }
#pragma unroll
    for (int p = 0; p < TBN / 32; ++p) {
      int rb = wave * (TBN / 4) + p * 8;
      async16(Bt + (n0 + rb + lrow) * (long)K + k0 + scol * 8, &Bs[rb * 64]);
    }
    __syncthreads();
#pragma unroll
    for (int ks = 0; ks < 2; ++ks) {
      bf16x8 af[MI], bfv[NI];
#pragma unroll
      for (int mi = 0; mi < MI; ++mi) {
        int r = wr + mi * 16 + l16;
        af[mi] = *(const bf16x8*)(&As[r * 64 + ((ks * 4 + quad) ^ (r & 7)) * 8]);
      }
#pragma unroll
      for (int ni = 0; ni < NI; ++ni) {
        int r = wc + ni * 16 + l16;
        bfv[ni] = *(const bf16x8*)(&Bs[r * 64 + ((ks * 4 + quad) ^ (r & 7)) * 8]);
      }
#pragma unroll
      for (int mi = 0; mi < MI; ++mi)
#pragma unroll
        for (int ni = 0; ni < NI; ++ni)
          acc[mi][ni] = __builtin_amdgcn_mfma_f32_16x16x32_bf16(af[mi], bfv[ni], acc[mi][ni], 0, 0, 0);
    }
    __syncthreads();
  }

#pragma unroll
  for (int ni = 0; ni < NI; ++ni) {
    long col = n0 + wc + ni * 16 + l16;
    float bv = bias[col];
#pragma unroll
    for (int mi = 0; mi < MI; ++mi) {
      long rowb = m0 + wr + mi * 16 + quad * 4;
#pragma unroll
      for (int r = 0; r < 4; ++r) {
        float v = acc[mi][ni][r] + bv;
        if (OUTBF) ((unsigned short*)Cout)[(rowb + r) * N + col] = f32_to_bf16(v);
        else       ((float*)Cout)[(rowb + r) * N + col] = v;
      }
    }
  }
}

// ---------------------------------------------------------------------------
// Windowed flash attention, no-max softmax, 128 queries/block. (R7 exact)
// ---------------------------------------------------------------------------
__global__ __launch_bounds__(256) void attn_kernel(
    const unsigned short* __restrict__ qkv,
    unsigned short* __restrict__ aout)
{
  __shared__ unsigned short Ks[64 * 72];       // [key][d]
  __shared__ unsigned short Vt[64 * 72];       // [d][key^swz]
  __shared__ unsigned short Ps[4 * 16 * 72];   // per-wave [q][key]

  const int tid  = threadIdx.x;
  const int w    = tid >> 6;
  const int lane = tid & 63;
  const int quad = lane >> 4;
  const int l16  = lane & 15;

  const int blk = blockIdx.x;            // 512 = b(2) * h(16) * 16 q-blocks
  const int qb  = blk & 15;
  const int h   = (blk >> 4) & 15;
  const int b   = blk >> 8;

  const int  i0 = qb * 128;
  const long rowbase = (long)b * SEQ_L;

  // Q fragments for both subtiles: A[m=l16][k=quad*8+j] (+32)
  bf16x8 aq[2][2];
#pragma unroll
  for (int sub = 0; sub < 2; ++sub) {
    const unsigned short* qp =
        qkv + (rowbase + i0 + sub * 64 + w * 16 + l16) * 3072 + h * 64 + quad * 8;
    aq[sub][0] = *(const bf16x8*)(qp);
    aq[sub][1] = *(const bf16x8*)(qp + 32);
  }

  f32x4 o[2][4];
  float l_i[2][4];
#pragma unroll
  for (int sub = 0; sub < 2; ++sub)
#pragma unroll
    for (int ni = 0; ni < 4; ++ni)
#pragma unroll
      for (int r = 0; r < 4; ++r) { o[sub][ni][r] = 0.0f; l_i[sub][r] = 0.0f; }

  unsigned short* psw = &Ps[w * 16 * 72];

  const int j_begin = (i0 >= WIN) ? i0 - WIN : 0;

  for (int j0 = j_begin; j0 < i0 + 128; j0 += 64) {
    __syncthreads();   // previous tile's Ks/Vt reads done
    // ---- stage K tile + transposed V tile ----
#pragma unroll
    for (int p = 0; p < 2; ++p) {
      int c = p * 256 + tid, row = c >> 3, col8 = c & 7;
      const unsigned short* base = qkv + (rowbase + j0 + row) * 3072 + h * 64 + col8 * 8;
      *(uint4*)(&Ks[row * 72 + col8 * 8]) = *(const uint4*)(base + 1024);
      unsigned short tmp[8];
      *(uint4*)tmp = *(const uint4*)(base + 2048);
      int rsw = row ^ (col8 << 3);
#pragma unroll
      for (int e = 0; e < 8; ++e)
        Vt[(col8 * 8 + e) * 72 + rsw] = tmp[e];
    }
    __syncthreads();

    // ---- hoist K and V fragments (shared by both subtiles) ----
    bf16x8 kf[4][2];
#pragma unroll
    for (int g = 0; g < 4; ++g) {
      kf[g][0] = *(const bf16x8*)(&Ks[(g * 16 + l16) * 72 + quad * 8]);
      kf[g][1] = *(const bf16x8*)(&Ks[(g * 16 + l16) * 72 + 32 + quad * 8]);
    }
    bf16x8 vf[2][4];
#pragma unroll
    for (int kk = 0; kk < 2; ++kk)
#pragma unroll
      for (int ni = 0; ni < 4; ++ni) {
        int d  = ni * 16 + l16;
        int rb = (kk * 32 + quad * 8) ^ (((d >> 3) & 7) << 3);
        vf[kk][ni] = *(const bf16x8*)(&Vt[d * 72 + rb]);
      }

#pragma unroll
    for (int sub = 0; sub < 2; ++sub) {
      const int i0s = i0 + sub * 64 + w * 16;
      if (j0 > i0s + 15) continue;              // entirely in the future
      if (j0 + 63 + WIN <= i0s) continue;       // entirely before the window

      // ---- S = Q.K^T ----
      f32x4 s[4];
#pragma unroll
      for (int g = 0; g < 4; ++g) {
        f32x4 z;
#pragma unroll
        for (int r = 0; r < 4; ++r) z[r] = 0.0f;
        z = __builtin_amdgcn_mfma_f32_16x16x32_bf16(aq[sub][0], kf[g][0], z, 0, 0, 0);
        z = __builtin_amdgcn_mfma_f32_16x16x32_bf16(aq[sub][1], kf[g][1], z, 0, 0, 0);
        s[g] = z;
      }
      // ---- mask + exp (no max subtraction) + P write + local l ----
#pragma unroll
      for (int g = 0; g < 4; ++g) {
        int j = j0 + g * 16 + l16;
#pragma unroll
        for (int r = 0; r < 4; ++r) {
          int i = i0s + quad * 4 + r;
          bool ok = (j <= i) && (j > i - WIN);
          float e = ok ? __expf(s[g][r] * 0.125f) : 0.0f;
          psw[(quad * 4 + r) * 72 + g * 16 + l16] = f32_to_bf16(e);
          l_i[sub][r] += e;
        }
      }
      asm volatile("s_waitcnt lgkmcnt(0)" ::: "memory");  // P visible to own wave
      // ---- O += P.V ----
#pragma unroll
      for (int kk = 0; kk < 2; ++kk) {
        bf16x8 ap = *(const bf16x8*)(&psw[l16 * 72 + kk * 32 + quad * 8]);
#pragma unroll
        for (int ni = 0; ni < 4; ++ni)
          o[sub][ni] = __builtin_amdgcn_mfma_f32_16x16x32_bf16(ap, vf[kk][ni], o[sub][ni], 0, 0, 0);
      }
    }
  }

  // ---- epilogue: one l-reduction, normalize, store bf16 [token][h*64+d] ----
#pragma unroll
  for (int sub = 0; sub < 2; ++sub)
#pragma unroll
    for (int r = 0; r < 4; ++r) {
      float rs = l_i[sub][r];
      rs += __shfl_xor(rs, 1);
      rs += __shfl_xor(rs, 2);
      rs += __shfl_xor(rs, 4);
      rs += __shfl_xor(rs, 8);
      float inv_l = 1.0f / rs;
      long row = rowbase + i0 + sub * 64 + w * 16 + quad * 4 + r;
#pragma unroll
      for (int ni = 0; ni < 4; ++ni)
        aout[row * 1024 + h * 64 + ni * 16 + l16] = f32_to_bf16(o[sub][ni][r] * inv_l);
    }
}

// ---------------------------------------------------------------------------
extern "C" void kernel_launch(void* const* d_in, const int* in_sizes, int n_in,
                              void* d_out, int out_size, void* d_ws, size_t ws_size,
                              hipStream_t stream)
{
  const float* x  = (const float*)d_in[0];   // [2,2048,1024]
  const float* w1 = (const float*)d_in[1];   // [3072,1024]
  const float* b1 = (const float*)d_in[2];   // [3072]
  const float* w2 = (const float*)d_in[3];   // [1024,1024]
  const float* b2 = (const float*)d_in[4];   // [1024]
  float* out = (float*)d_out;                // [2,2048,1024] fp32

  char* ws = (char*)d_ws;
  unsigned short* x_bf   = (unsigned short*)(ws);              //  8.39 MB
  unsigned short* w1_bf  = (unsigned short*)(ws + 8388608);    //  6.29 MB
  unsigned short* w2_bf  = (unsigned short*)(ws + 14680064);   //  2.10 MB
  unsigned short* qkv_bf = (unsigned short*)(ws + 16777216);   // 25.17 MB
  unsigned short* at_bf  = (unsigned short*)(ws + 41943040);   //  8.39 MB

  cast_all<<<8192, 256, 0, stream>>>(x, x_bf, w1, w1_bf, w2, w2_bf);

  dim3 g1(3072 / 192, 4096 / 256);   // (16, 16) = 256 blocks, 512 thr
  gemm_qkv<<<g1, 512, 0, stream>>>(x_bf, w1_bf, b1, qkv_bf, 4096, 3072, 1024);

  attn_kernel<<<512, 256, 0, stream>>>(qkv_bf, at_bf);

  dim3 g2(1024 / 64, 4096 / 64);     // (16, 64) = 1024 blocks
  gemm_nt<64, 64, 2, 2, 0><<<g2, 256, 0, stream>>>(at_bf, w2_bf, b2, out, 4096, 1024, 1024);
}